// Round 15
// baseline (1391.201 us; speedup 1.0000x reference)
//
#include <hip/hip_runtime.h>
#include <hip/hip_bf16.h>
#include <cfloat>

#define BB 4
#define NN 2048
#define KNN 20
#define KTOP 14          // ceil(20*2/3)
#define EPSBN 1e-5f
#define SLOPE 0.2f

// ---------------- xx for layer-1 input (C=3), good parallelism ------------
__global__ void k_xx3(const float* __restrict__ x, float* __restrict__ xx) {
  int t = blockIdx.x * 64 + threadIdx.x;     // 8192 threads
  int b = t >> 11, n = t & 2047;
  const float* xb = x + (long)b * (3L * NN) + n;
  float v0 = xb[0], v1 = xb[NN], v2 = xb[2 * NN];
  xx[t] = v0 * v0 + v1 * v1 + v2 * v2;
}

// ---- local argmax over 32 register values (static-index tree) ------------
__device__ __forceinline__ void top1_tree(const float v[32], float& bv, int& bi) {
  float mv[16]; int mi[16];
#pragma unroll
  for (int s = 0; s < 16; ++s) {
    mi[s] = (v[2 * s] >= v[2 * s + 1]) ? 2 * s : 2 * s + 1;
    mv[s] = fmaxf(v[2 * s], v[2 * s + 1]);
  }
#pragma unroll
  for (int s = 0; s < 8; ++s) {
    mi[s] = (mv[2 * s] >= mv[2 * s + 1]) ? mi[2 * s] : mi[2 * s + 1];
    mv[s] = fmaxf(mv[2 * s], mv[2 * s + 1]);
  }
#pragma unroll
  for (int s = 0; s < 4; ++s) {
    mi[s] = (mv[2 * s] >= mv[2 * s + 1]) ? mi[2 * s] : mi[2 * s + 1];
    mv[s] = fmaxf(mv[2 * s], mv[2 * s + 1]);
  }
  int i01 = (mv[0] >= mv[1]) ? mi[0] : mi[1];
  float v01 = fmaxf(mv[0], mv[1]);
  int i23 = (mv[2] >= mv[3]) ? mi[2] : mi[3];
  float v23 = fmaxf(mv[2], mv[3]);
  bi = (v01 >= v23) ? i01 : i23;
  bv = fmaxf(v01, v23);
}

__device__ __forceinline__ void remove_slot(float v[32], int bi) {
#pragma unroll
  for (int s = 0; s < 32; ++s)
    if (s == bi) v[s] = -FLT_MAX;
}

// ---- top-20 SET extraction, register-resident with lazy top-2 cache ------
// Tile is read-only: suppression + removals live in registers. Per round the
// common path is butterfly+ballot+promote; tree refill only on 2nd+ win of a
// lane (wave-uniformly skipped otherwise).
__device__ __forceinline__ void sel_reg(const float* __restrict__ trow,
                                        const int* __restrict__ lrow,
                                        int keepv, int lane,
                                        int* __restrict__ orow) {
  int base = 4 * lane;
  float v[32];
#pragma unroll
  for (int q = 0; q < 8; ++q) {
    float4 lv = *(const float4*)(trow + 256 * q + base);
    int4 kv = *(const int4*)(lrow + 256 * q + base);
    v[4 * q + 0] = (((kv.x != 0) ? 1 : 0) == keepv) ? lv.x : -FLT_MAX;
    v[4 * q + 1] = (((kv.y != 0) ? 1 : 0) == keepv) ? lv.y : -FLT_MAX;
    v[4 * q + 2] = (((kv.z != 0) ? 1 : 0) == keepv) ? lv.z : -FLT_MAX;
    v[4 * q + 3] = (((kv.w != 0) ? 1 : 0) == keepv) ? lv.w : -FLT_MAX;
  }
  float bv1, bv2; int li1, li2;
  top1_tree(v, bv1, li1); remove_slot(v, li1);
  top1_tree(v, bv2, li2); remove_slot(v, li2);
  bool has2 = true;
  for (int t = 0; t < KNN; ++t) {
    float gv = bv1;
#pragma unroll
    for (int d = 1; d < 64; d <<= 1) gv = fmaxf(gv, __shfl_xor(gv, d));
    unsigned long long mk = __ballot(bv1 == gv);
    int wl = (int)(__ffsll((long long)mk) - 1);
    int jloc = 256 * (li1 >> 2) + base + (li1 & 3);
    int bj = __shfl(jloc, wl);
    if (lane == 0) orow[t] = bj;
    bool iwin = (lane == wl);
    bool refill = iwin && !has2;
    if (iwin && has2) { bv1 = bv2; li1 = li2; has2 = false; }
    if (__ballot(refill)) {           // usually 0 -> branch skipped
      if (refill) { top1_tree(v, bv1, li1); remove_slot(v, li1); }
    }
  }
}

// ---- pd 4-row tile GEMM -> LDS (tile stays pristine for selection) -------
template <int C>
__device__ __forceinline__ void pd_tile(
    float (*tile)[NN], float (*a_lds)[4],
    const float* __restrict__ xb, const float* __restrict__ xxb,
    int i0, int tid) {
  for (int jt = 0; jt < NN; jt += 1024) {
    float acc[4][4];
#pragma unroll
    for (int r = 0; r < 4; ++r)
#pragma unroll
      for (int s = 0; s < 4; ++s) acc[r][s] = 0.f;
#pragma unroll 4
    for (int c = 0; c < C; ++c) {
      float4 a = *(const float4*)&a_lds[c][0];                     // LDS broadcast
      float4 h = *(const float4*)&xb[(long)c * NN + jt + tid * 4]; // coalesced
      acc[0][0] += a.x * h.x; acc[0][1] += a.x * h.y; acc[0][2] += a.x * h.z; acc[0][3] += a.x * h.w;
      acc[1][0] += a.y * h.x; acc[1][1] += a.y * h.y; acc[1][2] += a.y * h.z; acc[1][3] += a.y * h.w;
      acc[2][0] += a.z * h.x; acc[2][1] += a.z * h.y; acc[2][2] += a.z * h.z; acc[2][3] += a.z * h.w;
      acc[3][0] += a.w * h.x; acc[3][1] += a.w * h.y; acc[3][2] += a.w * h.z; acc[3][3] += a.w * h.w;
    }
    float4 xxj = *(const float4*)&xxb[jt + tid * 4];
#pragma unroll
    for (int r = 0; r < 4; ++r) {
      float xxi = xxb[i0 + r];
      float4 o;
      o.x = 2.f * acc[r][0] - xxi - xxj.x;
      o.y = 2.f * acc[r][1] - xxi - xxj.y;
      o.z = 2.f * acc[r][2] - xxi - xxj.z;
      o.w = 2.f * acc[r][3] - xxi - xxj.w;
      *(float4*)&tile[r][jt + tid * 4] = o;
    }
  }
}

// -------- layer-1 dual kNN (both masks; single pd, register selection) ----
template <int C>
__global__ __launch_bounds__(256) void k_knn_dual(
    const float* __restrict__ xbase, long bstride, const float* __restrict__ xxbase,
    const int* __restrict__ lidx,
    int* __restrict__ idxA /*keep=1*/, int* __restrict__ idxB /*keep=0*/) {
  __shared__ float tile[4][NN];
  __shared__ float a_lds[C][4];
  int b = blockIdx.y;
  int i0 = blockIdx.x * 4;
  const float* xb = xbase + (long)b * bstride;
  const float* xxb = xxbase + b * NN;
  int tid = threadIdx.x, wid = tid >> 6, lane = tid & 63;
  for (int t = tid; t < 4 * C; t += 256) {
    int c = t >> 2, r = t & 3;
    a_lds[c][r] = xb[(long)c * NN + i0 + r];
  }
  __syncthreads();
  pd_tile<C>(tile, a_lds, xb, xxb, i0, tid);
  __syncthreads();
  const int* lrow = lidx + b * NN;
  int i = i0 + wid;
  const float* trow = &tile[wid][0];
  sel_reg(trow, lrow, 1, lane, idxA + ((long)b * NN + i) * KNN);
  sel_reg(trow, lrow, 0, lane, idxB + ((long)b * NN + i) * KNN);
}

// -------- paired kNN: local(keep=1) + global(keep=0) in one dispatch ------
template <int C>
__global__ __launch_bounds__(256) void k_knn2(
    const float* __restrict__ xA, const float* __restrict__ xxA,
    int* __restrict__ idxA,
    const float* __restrict__ xB, const float* __restrict__ xxB,
    int* __restrict__ idxB, long bstride, const int* __restrict__ lidx) {
  __shared__ float tile[4][NN];
  __shared__ float a_lds[C][4];
  int half = blockIdx.z;
  const float* xbase = half ? xB : xA;
  const float* xxbase = half ? xxB : xxA;
  int keepv = half ? 0 : 1;
  int* idxO = half ? idxB : idxA;
  int b = blockIdx.y;
  int i0 = blockIdx.x * 4;
  const float* xb = xbase + (long)b * bstride;
  const float* xxb = xxbase + b * NN;
  int tid = threadIdx.x, wid = tid >> 6, lane = tid & 63;
  for (int t = tid; t < 4 * C; t += 256) {
    int c = t >> 2, r = t & 3;
    a_lds[c][r] = xb[(long)c * NN + i0 + r];
  }
  __syncthreads();
  pd_tile<C>(tile, a_lds, xb, xxb, i0, tid);
  __syncthreads();
  const int* lrow = lidx + b * NN;
  int i = i0 + wid;
  sel_reg(&tile[wid][0], lrow, keepv, lane, idxO + ((long)b * NN + i) * KNN);
}

// ---------------- smoothed source: mean of top-14 of 20 gathered ----------
__global__ void k_smooth(const float* __restrict__ x, long bstride, int C,
                         const int* __restrict__ idx, float* __restrict__ src) {
  long t = (long)blockIdx.x * blockDim.x + threadIdx.x;
  if (t >= (long)BB * C * NN) return;
  int n = (int)(t % NN);
  int c = (int)((t / NN) % C);
  int b = (int)(t / ((long)NN * C));
  const int* id = idx + ((long)b * NN + n) * KNN;
  const float* xb = x + (long)b * bstride + (long)c * NN;
  float v[KNN]; float sum = 0.f;
#pragma unroll
  for (int kk = 0; kk < KNN; ++kk) { v[kk] = xb[id[kk]]; sum += v[kk]; }
  int r0 = -1, r1 = -1, r2 = -1, r3 = -1, r4 = -1, r5 = -1;
#pragma unroll
  for (int r = 0; r < KNN - KTOP; ++r) {
    float mvv = FLT_MAX; int mi = -1;
#pragma unroll
    for (int j = 0; j < KNN; ++j) {
      if (j == r0 || j == r1 || j == r2 || j == r3 || j == r4 || j == r5) continue;
      if (v[j] < mvv) { mvv = v[j]; mi = j; }
    }
    sum -= mvv;
    if (r == 0) r0 = mi; else if (r == 1) r1 = mi; else if (r == 2) r2 = mi;
    else if (r == 3) r3 = mi; else if (r == 4) r4 = mi; else r5 = mi;
  }
  src[((long)b * C + c) * NN + n] = sum * (1.f / KTOP);
}

// ---------------- ALL weight preps in one dispatch ------------------------
__global__ void k_wprep_all(
    const float* __restrict__ w1, const float* __restrict__ w2,
    const float* __restrict__ w3, const float* __restrict__ w4,
    const float* __restrict__ w5, const float* __restrict__ w6,
    const float* __restrict__ w7, const float* __restrict__ w8,
    float* __restrict__ wa, float* __restrict__ wd) {
  int L = blockIdx.y;
  const float* w; int O, C; long off;
  switch (L) {
    case 0: w = w1; O = 64;  C = 3;   off = 0;     break;
    case 1: w = w2; O = 64;  C = 64;  off = 192;   break;
    case 2: w = w3; O = 128; C = 64;  off = 4288;  break;
    case 3: w = w4; O = 256; C = 128; off = 12480; break;
    case 4: w = w5; O = 64;  C = 3;   off = 45248; break;
    case 5: w = w6; O = 64;  C = 64;  off = 45440; break;
    case 6: w = w7; O = 128; C = 64;  off = 49536; break;
    default: w = w8; O = 256; C = 128; off = 57728; break;
  }
  for (int t = blockIdx.x * blockDim.x + threadIdx.x; t < O * C;
       t += gridDim.x * blockDim.x) {
    int o = t / C, c = t % C;
    float a = w[(long)o * 2 * C + c];
    float bb = w[(long)o * 2 * C + C + c];
    wa[off + (long)c * O + o] = a;
    wd[off + (long)c * O + o] = bb - a;
  }
}

// ---------------- fused Zs/Zd GEMM: T[z][n][o] = M[z][c][n] . Wt[c][o] ----
template <int C>
__global__ __launch_bounds__(256) void k_zt2(
    const float* __restrict__ Ma, long mas,
    const float* __restrict__ Mb_, long mbs,
    const float* __restrict__ wa, const float* __restrict__ wd,
    int O, float* __restrict__ Zs, float* __restrict__ Zd) {
  constexpr int KC = (C >= 16) ? 16 : C;
  __shared__ float As[KC][64], Bs[KC][64];
  int z = blockIdx.z;
  int nyo = gridDim.y >> 1;
  int half = (blockIdx.y >= nyo) ? 1 : 0;
  int o0 = (half ? (blockIdx.y - nyo) : blockIdx.y) * 64;
  const float* M = half ? Mb_ : Ma;
  long ms = half ? mbs : mas;
  const float* Wt = half ? wd : wa;
  float* T = half ? Zd : Zs;
  const float* Mb = M + (long)z * ms;
  float* Tb = T + (long)z * NN * O;
  int tid = threadIdx.x;
  int tx = tid & 15, ty = tid >> 4;
  int n0 = blockIdx.x * 64;
  float acc[4][4];
#pragma unroll
  for (int r = 0; r < 4; ++r)
#pragma unroll
    for (int s = 0; s < 4; ++s) acc[r][s] = 0.f;
  for (int c0 = 0; c0 < C; c0 += KC) {
    for (int e = tid; e < KC * 64; e += 256) {
      int c = e >> 6, ii = e & 63;
      As[c][ii] = Mb[(long)(c0 + c) * NN + n0 + ii];
      Bs[c][ii] = Wt[(long)(c0 + c) * O + o0 + ii];
    }
    __syncthreads();
#pragma unroll
    for (int cc = 0; cc < KC; ++cc) {
      float4 a = *(const float4*)&As[cc][ty * 4];
      float4 h = *(const float4*)&Bs[cc][tx * 4];
      acc[0][0] += a.x * h.x; acc[0][1] += a.x * h.y; acc[0][2] += a.x * h.z; acc[0][3] += a.x * h.w;
      acc[1][0] += a.y * h.x; acc[1][1] += a.y * h.y; acc[1][2] += a.y * h.z; acc[1][3] += a.y * h.w;
      acc[2][0] += a.z * h.x; acc[2][1] += a.z * h.y; acc[2][2] += a.z * h.z; acc[2][3] += a.z * h.w;
      acc[3][0] += a.w * h.x; acc[3][1] += a.w * h.y; acc[3][2] += a.w * h.z; acc[3][3] += a.w * h.w;
    }
    __syncthreads();
  }
#pragma unroll
  for (int r = 0; r < 4; ++r) {
    float4 v; v.x = acc[r][0]; v.y = acc[r][1]; v.z = acc[r][2]; v.w = acc[r][3];
    *(float4*)&Tb[(long)(n0 + ty * 4 + r) * O + o0 + tx * 4] = v;
  }
}

// ---------------- gather + max/stats: y = Zs[idx[n,k]] + Zd[n] ------------
template <int O, int PTS>
__global__ __launch_bounds__(O) void k_gmax(
    const float* __restrict__ Zs, const float* __restrict__ Zd,
    const int* __restrict__ idx, float* __restrict__ ymax,
    float* __restrict__ stats) {
  int tid = threadIdx.x;
  int bn0 = blockIdx.x * PTS;
  int b = bn0 >> 11;
  long zbase = (long)b * NN * O;
  float ss = 0.f, sq = 0.f;
  for (int p = 0; p < PTS; ++p) {
    int bn = bn0 + p;
    const int* ir = idx + (long)bn * KNN;
    float zd = Zd[(long)bn * O + tid];
    float smax = -FLT_MAX;
#pragma unroll
    for (int k = 0; k < KNN; ++k) {
      float y = Zs[zbase + (long)ir[k] * O + tid] + zd;
      smax = fmaxf(smax, y); ss += y; sq += y * y;
    }
    ymax[(long)bn * O + tid] = smax;
  }
  atomicAdd(&stats[tid], ss);
  atomicAdd(&stats[O + tid], sq);
}

// ---------------- BN(ymax)+leaky -> layer out; optional xx accumulation ---
__global__ void k_bnmax(const float* __restrict__ ymax, const float* __restrict__ stats,
                        int O, float invcnt, float* __restrict__ out, long out_bstride,
                        float* __restrict__ xxout) {
  long t = (long)blockIdx.x * blockDim.x + threadIdx.x;
  if (t >= (long)BB * O * NN) return;
  int n = (int)(t % NN);
  int o = (int)((t / NN) % O);
  int b = (int)(t / ((long)NN * O));
  float mu = stats[o] * invcnt;
  float var = stats[O + o] * invcnt - mu * mu;
  float rs = rsqrtf(var + EPSBN);
  float v = (ymax[((long)b * NN + n) * O + o] - mu) * rs;
  v = v >= 0.f ? v : SLOPE * v;
  out[(long)b * out_bstride + (long)o * NN + n] = v;
  if (xxout) atomicAdd(&xxout[b * NN + n], v * v);
}

// ---------------- merge + w9 conv: 64o x 128p tile, 8x4 micro-tile --------
__global__ __launch_bounds__(256) void k_gemm9(
    const float* __restrict__ W, const float* __restrict__ xl,
    const float* __restrict__ xg, const int* __restrict__ lidx,
    float* __restrict__ h2, float* __restrict__ stats) {
  __shared__ float Ws[16][72];    // [c][o]  64 o
  __shared__ float Hs[16][132];   // [c][p]  128 p
  int tid = threadIdx.x;
  int tx = tid & 31, ty = tid >> 5;           // p-group (4), o-group (8)
  int p0 = blockIdx.x * 128, o0 = blockIdx.y * 64;
  int b = p0 >> 11, n0 = p0 & 2047;
  int sp = tid & 127, scq = (tid >> 7) * 8;
  const float* hbase;
  {
    int pt = p0 + sp;
    hbase = (lidx[pt] ? xl : xg) + (long)b * (512L * NN) + (pt & 2047);
  }
  int wo = tid >> 2, wc = (tid & 3) * 4;
  float acc[8][4];
#pragma unroll
  for (int i = 0; i < 8; ++i)
#pragma unroll
    for (int j = 0; j < 4; ++j) acc[i][j] = 0.f;

  for (int c0 = 0; c0 < 512; c0 += 16) {
    float4 wv = *(const float4*)(W + (long)(o0 + wo) * 512 + c0 + wc);
    Ws[wc + 0][wo] = wv.x; Ws[wc + 1][wo] = wv.y;
    Ws[wc + 2][wo] = wv.z; Ws[wc + 3][wo] = wv.w;
    long crow = (long)(c0 + scq) * NN;
#pragma unroll
    for (int e = 0; e < 8; ++e) Hs[scq + e][sp] = hbase[crow + (long)e * NN];
    __syncthreads();
#pragma unroll
    for (int cc = 0; cc < 16; ++cc) {
      float4 a0 = *(const float4*)&Ws[cc][ty * 8];
      float4 a1 = *(const float4*)&Ws[cc][ty * 8 + 4];
      float4 h = *(const float4*)&Hs[cc][tx * 4];
      acc[0][0] += a0.x * h.x; acc[0][1] += a0.x * h.y; acc[0][2] += a0.x * h.z; acc[0][3] += a0.x * h.w;
      acc[1][0] += a0.y * h.x; acc[1][1] += a0.y * h.y; acc[1][2] += a0.y * h.z; acc[1][3] += a0.y * h.w;
      acc[2][0] += a0.z * h.x; acc[2][1] += a0.z * h.y; acc[2][2] += a0.z * h.z; acc[2][3] += a0.z * h.w;
      acc[3][0] += a0.w * h.x; acc[3][1] += a0.w * h.y; acc[3][2] += a0.w * h.z; acc[3][3] += a0.w * h.w;
      acc[4][0] += a1.x * h.x; acc[4][1] += a1.x * h.y; acc[4][2] += a1.x * h.z; acc[4][3] += a1.x * h.w;
      acc[5][0] += a1.y * h.x; acc[5][1] += a1.y * h.y; acc[5][2] += a1.y * h.z; acc[5][3] += a1.y * h.w;
      acc[6][0] += a1.z * h.x; acc[6][1] += a1.z * h.y; acc[6][2] += a1.z * h.z; acc[6][3] += a1.z * h.w;
      acc[7][0] += a1.w * h.x; acc[7][1] += a1.w * h.y; acc[7][2] += a1.w * h.z; acc[7][3] += a1.w * h.w;
    }
    __syncthreads();
  }
#pragma unroll
  for (int i = 0; i < 8; ++i) {
    int o = o0 + ty * 8 + i;
    float4 v; v.x = acc[i][0]; v.y = acc[i][1]; v.z = acc[i][2]; v.w = acc[i][3];
    *(float4*)&h2[((long)b * 1024 + o) * NN + n0 + tx * 4] = v;
    float ss = acc[i][0] + acc[i][1] + acc[i][2] + acc[i][3];
    float sq = acc[i][0] * acc[i][0] + acc[i][1] * acc[i][1] +
               acc[i][2] * acc[i][2] + acc[i][3] * acc[i][3];
    for (int d = 16; d > 0; d >>= 1) {
      ss += __shfl_down(ss, d, 32);
      sq += __shfl_down(sq, d, 32);
    }
    if (tx == 0) {
      atomicAdd(&stats[o], ss);
      atomicAdd(&stats[1024 + o], sq);
    }
  }
}

// ---------------- BN+leaky (on the fly) + max/mean pool over N ------------
__global__ void k_gpool(const float* __restrict__ h2, const float* __restrict__ stats,
                        float* __restrict__ g) {
  int b = blockIdx.x / 1024, o = blockIdx.x % 1024;
  int tid = threadIdx.x;
  float mu = stats[o] * (1.f / 8192.f);
  float var = stats[1024 + o] * (1.f / 8192.f) - mu * mu;
  float rs = rsqrtf(var + EPSBN);
  const float* hr = h2 + ((long)b * 1024 + o) * NN;
  float mx = -FLT_MAX, sm = 0.f;
  for (int n = tid; n < NN; n += 256) {
    float v = (hr[n] - mu) * rs; v = v >= 0.f ? v : SLOPE * v;
    mx = fmaxf(mx, v); sm += v;
  }
  __shared__ float smx[256], ssm[256];
  smx[tid] = mx; ssm[tid] = sm; __syncthreads();
  for (int s = 128; s > 0; s >>= 1) {
    if (tid < s) { smx[tid] = fmaxf(smx[tid], smx[tid + s]); ssm[tid] += ssm[tid + s]; }
    __syncthreads();
  }
  if (tid == 0) { g[b * 2048 + o] = smx[0]; g[b * 2048 + 1024 + o] = ssm[0] * (1.f / NN); }
}

// ---------------- head: linear (+bias) (+BN over batch of 4, leaky) -------
__global__ void k_head(const float* __restrict__ gin, int CIN, const float* __restrict__ wl,
                       const float* __restrict__ bias, float* __restrict__ gout, int do_bn) {
  int f = blockIdx.x, tid = threadIdx.x, F = gridDim.x;
  const float* wr = wl + (long)f * CIN;
  float a0 = 0, a1 = 0, a2 = 0, a3 = 0;
  for (int c = tid; c < CIN; c += 256) {
    float wv = wr[c];
    a0 += wv * gin[c];         a1 += wv * gin[CIN + c];
    a2 += wv * gin[2 * CIN + c]; a3 += wv * gin[3 * CIN + c];
  }
  __shared__ float s0[256], s1[256], s2[256], s3[256];
  s0[tid] = a0; s1[tid] = a1; s2[tid] = a2; s3[tid] = a3; __syncthreads();
  for (int s = 128; s > 0; s >>= 1) {
    if (tid < s) { s0[tid] += s0[tid + s]; s1[tid] += s1[tid + s];
                   s2[tid] += s2[tid + s]; s3[tid] += s3[tid + s]; }
    __syncthreads();
  }
  if (tid == 0) {
    float z0 = s0[0], z1 = s1[0], z2 = s2[0], z3 = s3[0];
    if (bias) { float bb = bias[f]; z0 += bb; z1 += bb; z2 += bb; z3 += bb; }
    if (do_bn) {
      float mu = 0.25f * (z0 + z1 + z2 + z3);
      float var = 0.25f * (z0 * z0 + z1 * z1 + z2 * z2 + z3 * z3) - mu * mu;
      float rs = rsqrtf(var + EPSBN);
      z0 = (z0 - mu) * rs; z1 = (z1 - mu) * rs; z2 = (z2 - mu) * rs; z3 = (z3 - mu) * rs;
      z0 = z0 >= 0.f ? z0 : SLOPE * z0; z1 = z1 >= 0.f ? z1 : SLOPE * z1;
      z2 = z2 >= 0.f ? z2 : SLOPE * z2; z3 = z3 >= 0.f ? z3 : SLOPE * z3;
    }
    gout[0 * F + f] = z0; gout[1 * F + f] = z1; gout[2 * F + f] = z2; gout[3 * F + f] = z3;
  }
}

extern "C" void kernel_launch(void* const* d_in, const int* in_sizes, int n_in,
                              void* d_out, int out_size, void* d_ws, size_t ws_size,
                              hipStream_t stream) {
  const float* x   = (const float*)d_in[0];
  const int*   lidx= (const int*)d_in[1];
  const float* w1  = (const float*)d_in[3];
  const float* w2  = (const float*)d_in[4];
  const float* w3  = (const float*)d_in[5];
  const float* w4  = (const float*)d_in[6];
  const float* w5  = (const float*)d_in[7];
  const float* w6  = (const float*)d_in[8];
  const float* w7  = (const float*)d_in[9];
  const float* w8  = (const float*)d_in[10];
  const float* w9  = (const float*)d_in[11];
  const float* l1w = (const float*)d_in[12];
  const float* l2w = (const float*)d_in[13];
  const float* l2b = (const float*)d_in[14];
  const float* l3w = (const float*)d_in[15];
  const float* l3b = (const float*)d_in[16];
  float* out = (float*)d_out;

  float* ws    = (float*)d_ws;
  float* xxall = ws;                          // 7 * 8192 = 57344 (zeroed)
  float* stats = ws + 57344;                  // 4096 (zeroed)
  int*   idxb  = (int*)(ws + 61440);          // 163840 ints
  float* xloc  = ws + 225280;                 // 4,194,304
  float* xglb  = ws + 4419584;                // 4,194,304
  float* big   = ws + 8613888;                // 8,388,608 multi-use
  float* g     = ws + 17002496;               // 8192
  float* g1    = ws + 17010688;               // 2048
  float* g2    = ws + 17012736;               // 1024
  float* waall = ws + 17013760;               // 90496
  float* wdall = ws + 17104256;               // 90496

  float* srcb  = big;
  float* Zs    = big + 1048576;
  float* Zd    = big + 3145728;
  float* ymaxb = big + 5242880;
  int*   idxG2 = (int*)(big + 7340032);       // 163840 ints (dead until h2)
  float* h2    = big;
  int*   idxG  = (int*)xglb;                  // parked until G1 bnmax

  // xx slices
  float* xxS0 = xxall;
  float* xxS1 = xxall + 8192;
  float* xxS2 = xxall + 16384;
  float* xxS3 = xxall + 24576;
  float* xxS4 = xxall + 32768;
  float* xxS5 = xxall + 40960;
  float* xxS6 = xxall + 49152;

  // per-layer stats slices
  float* SL1 = stats + 0;    float* SL2 = stats + 128;
  float* SL3 = stats + 256;  float* SL4 = stats + 512;
  float* SG1 = stats + 1024; float* SG2 = stats + 1152;
  float* SG3 = stats + 1280; float* SG4 = stats + 1536;
  float* S9  = stats + 2048;

  const float invE = 1.f / (BB * NN * KNN);
  const long XS0 = 3L * NN;
  const long XS  = 512L * NN;
  const dim3 gknn(NN / 4, BB);       // layer-1 dual
  const dim3 gknn2(NN / 4, BB, 2);   // paired branches

  // ===== setup =====
  hipMemsetAsync(ws, 0, 61440 * sizeof(float), stream);
  k_wprep_all<<<dim3(128, 8), 256, 0, stream>>>(w1, w2, w3, w4, w5, w6, w7, w8,
                                                waall, wdall);
  k_xx3<<<128, 64, 0, stream>>>(x, xxS0);

  // ===== layer-1 kNN (both masks) =====
  k_knn_dual<3><<<gknn, 256, 0, stream>>>(x, XS0, xxS0, lidx, idxb, idxG);

  // ===== layer 1: L1 then G1 =====
  k_smooth<<<(BB * 3 * NN + 255) / 256, 256, 0, stream>>>(x, XS0, 3, idxb, srcb);
  k_zt2<3><<<dim3(32, 2, 4), 256, 0, stream>>>(srcb, 3L * NN, x, XS0,
                                               waall + 0, wdall + 0, 64, Zs, Zd);
  k_gmax<64, 8><<<BB * NN / 8, 64, 0, stream>>>(Zs, Zd, idxb, ymaxb, SL1);
  k_bnmax<<<(BB * 64 * NN + 255) / 256, 256, 0, stream>>>(ymaxb, SL1, 64, invE,
                                                          xloc + 0 * NN, XS, xxS1);
  k_zt2<3><<<dim3(32, 2, 4), 256, 0, stream>>>(x, XS0, x, XS0,
                                               waall + 45248, wdall + 45248, 64, Zs, Zd);
  k_gmax<64, 8><<<BB * NN / 8, 64, 0, stream>>>(Zs, Zd, idxG, ymaxb, SG1);
  k_bnmax<<<(BB * 64 * NN + 255) / 256, 256, 0, stream>>>(ymaxb, SG1, 64, invE,
                                                          xglb + 0 * NN, XS, xxS4);

  // ===== layer-2 kNN paired =====
  k_knn2<64><<<gknn2, 256, 0, stream>>>(xloc, xxS1, idxb,
                                        xglb, xxS4, idxG2, XS, lidx);
  // L2
  k_smooth<<<(BB * 64 * NN + 255) / 256, 256, 0, stream>>>(xloc, XS, 64, idxb, srcb);
  k_zt2<64><<<dim3(32, 2, 4), 256, 0, stream>>>(srcb, 64L * NN, xloc, XS,
                                                waall + 192, wdall + 192, 64, Zs, Zd);
  k_gmax<64, 8><<<BB * NN / 8, 64, 0, stream>>>(Zs, Zd, idxb, ymaxb, SL2);
  k_bnmax<<<(BB * 64 * NN + 255) / 256, 256, 0, stream>>>(ymaxb, SL2, 64, invE,
                                                          xloc + 64 * NN, XS, xxS2);
  // G2
  k_zt2<64><<<dim3(32, 2, 4), 256, 0, stream>>>(xglb, XS, xglb, XS,
                                                waall + 45440, wdall + 45440, 64, Zs, Zd);
  k_gmax<64, 8><<<BB * NN / 8, 64, 0, stream>>>(Zs, Zd, idxG2, ymaxb, SG2);
  k_bnmax<<<(BB * 64 * NN + 255) / 256, 256, 0, stream>>>(ymaxb, SG2, 64, invE,
                                                          xglb + 64 * NN, XS, xxS5);

  // ===== layer-3 kNN paired =====
  k_knn2<64><<<gknn2, 256, 0, stream>>>(xloc + 64 * NN, xxS2, idxb,
                                        xglb + 64 * NN, xxS5, idxG2, XS, lidx);
  // L3
  k_smooth<<<(BB * 64 * NN + 255) / 256, 256, 0, stream>>>(xloc + 64 * NN, XS, 64, idxb, srcb);
  k_zt2<64><<<dim3(32, 4, 4), 256, 0, stream>>>(srcb, 64L * NN, xloc + 64 * NN, XS,
                                                waall + 4288, wdall + 4288, 128, Zs, Zd);
  k_gmax<128, 16><<<BB * NN / 16, 128, 0, stream>>>(Zs, Zd, idxb, ymaxb, SL3);
  k_bnmax<<<(BB * 128 * NN + 255) / 256, 256, 0, stream>>>(ymaxb, SL3, 128, invE,
                                                           xloc + 128 * NN, XS, xxS3);
  // G3
  k_zt2<64><<<dim3(32, 4, 4), 256, 0, stream>>>(xglb + 64 * NN, XS, xglb + 64 * NN, XS,
                                                waall + 49536, wdall + 49536, 128, Zs, Zd);
  k_gmax<128, 16><<<BB * NN / 16, 128, 0, stream>>>(Zs, Zd, idxG2, ymaxb, SG3);
  k_bnmax<<<(BB * 128 * NN + 255) / 256, 256, 0, stream>>>(ymaxb, SG3, 128, invE,
                                                           xglb + 128 * NN, XS, xxS6);

  // ===== layer-4 kNN paired =====
  k_knn2<128><<<gknn2, 256, 0, stream>>>(xloc + 128 * NN, xxS3, idxb,
                                         xglb + 128 * NN, xxS6, idxG2, XS, lidx);
  // L4
  k_smooth<<<(BB * 128 * NN + 255) / 256, 256, 0, stream>>>(xloc + 128 * NN, XS, 128, idxb, srcb);
  k_zt2<128><<<dim3(32, 8, 4), 256, 0, stream>>>(srcb, 128L * NN, xloc + 128 * NN, XS,
                                                 waall + 12480, wdall + 12480, 256, Zs, Zd);
  k_gmax<256, 16><<<BB * NN / 16, 256, 0, stream>>>(Zs, Zd, idxb, ymaxb, SL4);
  k_bnmax<<<(BB * 256 * NN + 255) / 256, 256, 0, stream>>>(ymaxb, SL4, 256, invE,
                                                           xloc + 256 * NN, XS, nullptr);
  // G4
  k_zt2<128><<<dim3(32, 8, 4), 256, 0, stream>>>(xglb + 128 * NN, XS, xglb + 128 * NN, XS,
                                                 waall + 57728, wdall + 57728, 256, Zs, Zd);
  k_gmax<256, 16><<<BB * NN / 16, 256, 0, stream>>>(Zs, Zd, idxG2, ymaxb, SG4);
  k_bnmax<<<(BB * 256 * NN + 255) / 256, 256, 0, stream>>>(ymaxb, SG4, 256, invE,
                                                           xglb + 256 * NN, XS, nullptr);

  // ===== merge + w9 conv (SGEMM) + pool + head =====
  {
    dim3 g9(NN * BB / 128, 1024 / 64);
    k_gemm9<<<g9, 256, 0, stream>>>(w9, xloc, xglb, lidx, h2, S9);
  }
  k_gpool<<<BB * 1024, 256, 0, stream>>>(h2, S9, g);
  k_head<<<512, 256, 0, stream>>>(g, 2048, l1w, nullptr, g1, 1);
  k_head<<<256, 256, 0, stream>>>(g1, 512, l2w, l2b, g2, 1);
  k_head<<<40, 256, 0, stream>>>(g2, 256, l3w, l3b, out, 0);
}

// Round 16
// 1199.826 us; speedup vs baseline: 1.1595x; 1.1595x over previous
//
#include <hip/hip_runtime.h>
#include <hip/hip_bf16.h>
#include <cfloat>

#define BB 4
#define NN 2048
#define KNN 20
#define KTOP 14          // ceil(20*2/3)
#define EPSBN 1e-5f
#define SLOPE 0.2f

// ---------------- xx for layer-1 input (C=3), good parallelism ------------
__global__ void k_xx3(const float* __restrict__ x, float* __restrict__ xx) {
  int t = blockIdx.x * 64 + threadIdx.x;     // 8192 threads
  int b = t >> 11, n = t & 2047;
  const float* xb = x + (long)b * (3L * NN) + n;
  float v0 = xb[0], v1 = xb[NN], v2 = xb[2 * NN];
  xx[t] = v0 * v0 + v1 * v1 + v2 * v2;
}

// ---- in-place suppression of masked columns (own 32 cols per lane) -------
__device__ __forceinline__ void suppress(float* __restrict__ trow,
                                         const int* __restrict__ lrow,
                                         int keepv, int lane) {
  int base = 4 * lane;
#pragma unroll
  for (int q = 0; q < 8; ++q) {
    float4 lv = *(const float4*)(trow + 256 * q + base);
    int4 kv = *(const int4*)(lrow + 256 * q + base);
    lv.x = (((kv.x != 0) ? 1 : 0) == keepv) ? lv.x : -FLT_MAX;
    lv.y = (((kv.y != 0) ? 1 : 0) == keepv) ? lv.y : -FLT_MAX;
    lv.z = (((kv.z != 0) ? 1 : 0) == keepv) ? lv.z : -FLT_MAX;
    lv.w = (((kv.w != 0) ? 1 : 0) == keepv) ? lv.w : -FLT_MAX;
    *(float4*)(trow + 256 * q + base) = lv;
  }
}

// ---- top-20 SET extraction over a suppressed LDS row (round-14 proven) ---
__device__ __forceinline__ void sel_lds(float* __restrict__ trow, int lane,
                                        int* __restrict__ orow) {
  int base = 4 * lane;
  for (int t = 0; t < KNN; ++t) {
    float v[32];
#pragma unroll
    for (int q = 0; q < 8; ++q) {
      float4 lv = *(const float4*)(trow + 256 * q + base);
      v[4 * q + 0] = lv.x; v[4 * q + 1] = lv.y;
      v[4 * q + 2] = lv.z; v[4 * q + 3] = lv.w;
    }
    float mv[16]; int mi[16];
#pragma unroll
    for (int s = 0; s < 16; ++s) {
      mi[s] = (v[2 * s] >= v[2 * s + 1]) ? 2 * s : 2 * s + 1;
      mv[s] = fmaxf(v[2 * s], v[2 * s + 1]);
    }
#pragma unroll
    for (int s = 0; s < 8; ++s) {
      mi[s] = (mv[2 * s] >= mv[2 * s + 1]) ? mi[2 * s] : mi[2 * s + 1];
      mv[s] = fmaxf(mv[2 * s], mv[2 * s + 1]);
    }
#pragma unroll
    for (int s = 0; s < 4; ++s) {
      mi[s] = (mv[2 * s] >= mv[2 * s + 1]) ? mi[2 * s] : mi[2 * s + 1];
      mv[s] = fmaxf(mv[2 * s], mv[2 * s + 1]);
    }
    int i01 = (mv[0] >= mv[1]) ? mi[0] : mi[1];
    float v01 = fmaxf(mv[0], mv[1]);
    int i23 = (mv[2] >= mv[3]) ? mi[2] : mi[3];
    float v23 = fmaxf(mv[2], mv[3]);
    int li = (v01 >= v23) ? i01 : i23;
    float bv = fmaxf(v01, v23);
    float gv = bv;
#pragma unroll
    for (int d = 1; d < 64; d <<= 1) gv = fmaxf(gv, __shfl_xor(gv, d));
    unsigned long long mk = __ballot(bv == gv);
    int wl = (int)(__ffsll((long long)mk) - 1);
    int jloc = 256 * (li >> 2) + base + (li & 3);
    int bj = __shfl(jloc, wl);
    if (lane == 0) { orow[t] = bj; trow[bj] = -FLT_MAX; }
  }
}

// ---- pd 4-row tile GEMM -> LDS; A-rows via wave-uniform global loads -----
template <int C>
__device__ __forceinline__ void pd_tile(
    float (*tile)[NN],
    const float* __restrict__ xb, const float* __restrict__ xxb,
    int i0, int tid) {
  for (int jt = 0; jt < NN; jt += 1024) {
    float acc[4][4];
#pragma unroll
    for (int r = 0; r < 4; ++r)
#pragma unroll
      for (int s = 0; s < 4; ++s) acc[r][s] = 0.f;
#pragma unroll 4
    for (int c = 0; c < C; ++c) {
      float4 a = *(const float4*)&xb[(long)c * NN + i0];            // uniform, L1
      float4 h = *(const float4*)&xb[(long)c * NN + jt + tid * 4];  // coalesced
      acc[0][0] += a.x * h.x; acc[0][1] += a.x * h.y; acc[0][2] += a.x * h.z; acc[0][3] += a.x * h.w;
      acc[1][0] += a.y * h.x; acc[1][1] += a.y * h.y; acc[1][2] += a.y * h.z; acc[1][3] += a.y * h.w;
      acc[2][0] += a.z * h.x; acc[2][1] += a.z * h.y; acc[2][2] += a.z * h.z; acc[2][3] += a.z * h.w;
      acc[3][0] += a.w * h.x; acc[3][1] += a.w * h.y; acc[3][2] += a.w * h.z; acc[3][3] += a.w * h.w;
    }
    float4 xxj = *(const float4*)&xxb[jt + tid * 4];
#pragma unroll
    for (int r = 0; r < 4; ++r) {
      float xxi = xxb[i0 + r];
      float4 o;
      o.x = 2.f * acc[r][0] - xxi - xxj.x;
      o.y = 2.f * acc[r][1] - xxi - xxj.y;
      o.z = 2.f * acc[r][2] - xxi - xxj.z;
      o.w = 2.f * acc[r][3] - xxi - xxj.w;
      *(float4*)&tile[r][jt + tid * 4] = o;
    }
  }
}

// -------- layer-1 dual kNN (both masks; recompute pd between passes) ------
template <int C>
__global__ __launch_bounds__(256) void k_knn_dual(
    const float* __restrict__ xbase, long bstride, const float* __restrict__ xxbase,
    const int* __restrict__ lidx,
    int* __restrict__ idxA /*keep=1*/, int* __restrict__ idxB /*keep=0*/) {
  __shared__ float tile[4][NN];              // 32 KB exactly
  int b = blockIdx.y;
  int i0 = blockIdx.x * 4;
  const float* xb = xbase + (long)b * bstride;
  const float* xxb = xxbase + b * NN;
  int tid = threadIdx.x, wid = tid >> 6, lane = tid & 63;
  const int* lrow = lidx + b * NN;
  int i = i0 + wid;
  for (int pass = 0; pass < 2; ++pass) {
    if (pass) __syncthreads();               // all waves done with pass 1
    pd_tile<C>(tile, xb, xxb, i0, tid);
    __syncthreads();
    float* trow = &tile[wid][0];
    int kvp = pass ? 0 : 1;
    int* ob = pass ? idxB : idxA;
    suppress(trow, lrow, kvp, lane);
    sel_lds(trow, lane, ob + ((long)b * NN + i) * KNN);
  }
}

// -------- paired kNN: local(keep=1) + global(keep=0) in one dispatch ------
template <int C>
__global__ __launch_bounds__(256) void k_knn2(
    const float* __restrict__ xA, const float* __restrict__ xxA,
    int* __restrict__ idxA,
    const float* __restrict__ xB, const float* __restrict__ xxB,
    int* __restrict__ idxB, long bstride, const int* __restrict__ lidx) {
  __shared__ float tile[4][NN];              // 32 KB exactly
  int half = blockIdx.z;
  const float* xbase = half ? xB : xA;
  const float* xxbase = half ? xxB : xxA;
  int keepv = half ? 0 : 1;
  int* idxO = half ? idxB : idxA;
  int b = blockIdx.y;
  int i0 = blockIdx.x * 4;
  const float* xb = xbase + (long)b * bstride;
  const float* xxb = xxbase + b * NN;
  int tid = threadIdx.x, wid = tid >> 6, lane = tid & 63;
  pd_tile<C>(tile, xb, xxb, i0, tid);
  __syncthreads();
  const int* lrow = lidx + b * NN;
  int i = i0 + wid;
  float* trow = &tile[wid][0];
  suppress(trow, lrow, keepv, lane);
  sel_lds(trow, lane, idxO + ((long)b * NN + i) * KNN);
}

// ---------------- smoothed source: mean of top-14 of 20 gathered ----------
__global__ void k_smooth(const float* __restrict__ x, long bstride, int C,
                         const int* __restrict__ idx, float* __restrict__ src) {
  long t = (long)blockIdx.x * blockDim.x + threadIdx.x;
  if (t >= (long)BB * C * NN) return;
  int n = (int)(t % NN);
  int c = (int)((t / NN) % C);
  int b = (int)(t / ((long)NN * C));
  const int* id = idx + ((long)b * NN + n) * KNN;
  const float* xb = x + (long)b * bstride + (long)c * NN;
  float v[KNN]; float sum = 0.f;
#pragma unroll
  for (int kk = 0; kk < KNN; ++kk) { v[kk] = xb[id[kk]]; sum += v[kk]; }
  int r0 = -1, r1 = -1, r2 = -1, r3 = -1, r4 = -1, r5 = -1;
#pragma unroll
  for (int r = 0; r < KNN - KTOP; ++r) {
    float mvv = FLT_MAX; int mi = -1;
#pragma unroll
    for (int j = 0; j < KNN; ++j) {
      if (j == r0 || j == r1 || j == r2 || j == r3 || j == r4 || j == r5) continue;
      if (v[j] < mvv) { mvv = v[j]; mi = j; }
    }
    sum -= mvv;
    if (r == 0) r0 = mi; else if (r == 1) r1 = mi; else if (r == 2) r2 = mi;
    else if (r == 3) r3 = mi; else if (r == 4) r4 = mi; else r5 = mi;
  }
  src[((long)b * C + c) * NN + n] = sum * (1.f / KTOP);
}

// ---------------- ALL weight preps in one dispatch ------------------------
__global__ void k_wprep_all(
    const float* __restrict__ w1, const float* __restrict__ w2,
    const float* __restrict__ w3, const float* __restrict__ w4,
    const float* __restrict__ w5, const float* __restrict__ w6,
    const float* __restrict__ w7, const float* __restrict__ w8,
    float* __restrict__ wa, float* __restrict__ wd) {
  int L = blockIdx.y;
  const float* w; int O, C; long off;
  switch (L) {
    case 0: w = w1; O = 64;  C = 3;   off = 0;     break;
    case 1: w = w2; O = 64;  C = 64;  off = 192;   break;
    case 2: w = w3; O = 128; C = 64;  off = 4288;  break;
    case 3: w = w4; O = 256; C = 128; off = 12480; break;
    case 4: w = w5; O = 64;  C = 3;   off = 45248; break;
    case 5: w = w6; O = 64;  C = 64;  off = 45440; break;
    case 6: w = w7; O = 128; C = 64;  off = 49536; break;
    default: w = w8; O = 256; C = 128; off = 57728; break;
  }
  for (int t = blockIdx.x * blockDim.x + threadIdx.x; t < O * C;
       t += gridDim.x * blockDim.x) {
    int o = t / C, c = t % C;
    float a = w[(long)o * 2 * C + c];
    float bb = w[(long)o * 2 * C + C + c];
    wa[off + (long)c * O + o] = a;
    wd[off + (long)c * O + o] = bb - a;
  }
}

// ---------------- fused Zs/Zd GEMM: T[z][n][o] = M[z][c][n] . Wt[c][o] ----
template <int C>
__global__ __launch_bounds__(256) void k_zt2(
    const float* __restrict__ Ma, long mas,
    const float* __restrict__ Mb_, long mbs,
    const float* __restrict__ wa, const float* __restrict__ wd,
    int O, float* __restrict__ Zs, float* __restrict__ Zd) {
  constexpr int KC = (C >= 16) ? 16 : C;
  __shared__ float As[KC][64], Bs[KC][64];
  int z = blockIdx.z;
  int nyo = gridDim.y >> 1;
  int half = (blockIdx.y >= nyo) ? 1 : 0;
  int o0 = (half ? (blockIdx.y - nyo) : blockIdx.y) * 64;
  const float* M = half ? Mb_ : Ma;
  long ms = half ? mbs : mas;
  const float* Wt = half ? wd : wa;
  float* T = half ? Zd : Zs;
  const float* Mb = M + (long)z * ms;
  float* Tb = T + (long)z * NN * O;
  int tid = threadIdx.x;
  int tx = tid & 15, ty = tid >> 4;
  int n0 = blockIdx.x * 64;
  float acc[4][4];
#pragma unroll
  for (int r = 0; r < 4; ++r)
#pragma unroll
    for (int s = 0; s < 4; ++s) acc[r][s] = 0.f;
  for (int c0 = 0; c0 < C; c0 += KC) {
    for (int e = tid; e < KC * 64; e += 256) {
      int c = e >> 6, ii = e & 63;
      As[c][ii] = Mb[(long)(c0 + c) * NN + n0 + ii];
      Bs[c][ii] = Wt[(long)(c0 + c) * O + o0 + ii];
    }
    __syncthreads();
#pragma unroll
    for (int cc = 0; cc < KC; ++cc) {
      float4 a = *(const float4*)&As[cc][ty * 4];
      float4 h = *(const float4*)&Bs[cc][tx * 4];
      acc[0][0] += a.x * h.x; acc[0][1] += a.x * h.y; acc[0][2] += a.x * h.z; acc[0][3] += a.x * h.w;
      acc[1][0] += a.y * h.x; acc[1][1] += a.y * h.y; acc[1][2] += a.y * h.z; acc[1][3] += a.y * h.w;
      acc[2][0] += a.z * h.x; acc[2][1] += a.z * h.y; acc[2][2] += a.z * h.z; acc[2][3] += a.z * h.w;
      acc[3][0] += a.w * h.x; acc[3][1] += a.w * h.y; acc[3][2] += a.w * h.z; acc[3][3] += a.w * h.w;
    }
    __syncthreads();
  }
#pragma unroll
  for (int r = 0; r < 4; ++r) {
    float4 v; v.x = acc[r][0]; v.y = acc[r][1]; v.z = acc[r][2]; v.w = acc[r][3];
    *(float4*)&Tb[(long)(n0 + ty * 4 + r) * O + o0 + tx * 4] = v;
  }
}

// ---------------- gather + max/stats: y = Zs[idx[n,k]] + Zd[n] ------------
template <int O, int PTS>
__global__ __launch_bounds__(O) void k_gmax(
    const float* __restrict__ Zs, const float* __restrict__ Zd,
    const int* __restrict__ idx, float* __restrict__ ymax,
    float* __restrict__ stats) {
  int tid = threadIdx.x;
  int bn0 = blockIdx.x * PTS;
  int b = bn0 >> 11;
  long zbase = (long)b * NN * O;
  float ss = 0.f, sq = 0.f;
  for (int p = 0; p < PTS; ++p) {
    int bn = bn0 + p;
    const int* ir = idx + (long)bn * KNN;
    float zd = Zd[(long)bn * O + tid];
    float smax = -FLT_MAX;
#pragma unroll
    for (int k = 0; k < KNN; ++k) {
      float y = Zs[zbase + (long)ir[k] * O + tid] + zd;
      smax = fmaxf(smax, y); ss += y; sq += y * y;
    }
    ymax[(long)bn * O + tid] = smax;
  }
  atomicAdd(&stats[tid], ss);
  atomicAdd(&stats[O + tid], sq);
}

// ---------------- BN(ymax)+leaky -> layer out; optional xx accumulation ---
__global__ void k_bnmax(const float* __restrict__ ymax, const float* __restrict__ stats,
                        int O, float invcnt, float* __restrict__ out, long out_bstride,
                        float* __restrict__ xxout) {
  long t = (long)blockIdx.x * blockDim.x + threadIdx.x;
  if (t >= (long)BB * O * NN) return;
  int n = (int)(t % NN);
  int o = (int)((t / NN) % O);
  int b = (int)(t / ((long)NN * O));
  float mu = stats[o] * invcnt;
  float var = stats[O + o] * invcnt - mu * mu;
  float rs = rsqrtf(var + EPSBN);
  float v = (ymax[((long)b * NN + n) * O + o] - mu) * rs;
  v = v >= 0.f ? v : SLOPE * v;
  out[(long)b * out_bstride + (long)o * NN + n] = v;
  if (xxout) atomicAdd(&xxout[b * NN + n], v * v);
}

// ---------------- merge + w9 conv: 64o x 128p tile, 8x4 micro-tile --------
__global__ __launch_bounds__(256) void k_gemm9(
    const float* __restrict__ W, const float* __restrict__ xl,
    const float* __restrict__ xg, const int* __restrict__ lidx,
    float* __restrict__ h2, float* __restrict__ stats) {
  __shared__ float Ws[16][72];    // [c][o]  64 o
  __shared__ float Hs[16][132];   // [c][p]  128 p
  int tid = threadIdx.x;
  int tx = tid & 31, ty = tid >> 5;           // p-group (4), o-group (8)
  int p0 = blockIdx.x * 128, o0 = blockIdx.y * 64;
  int b = p0 >> 11, n0 = p0 & 2047;
  int sp = tid & 127, scq = (tid >> 7) * 8;
  const float* hbase;
  {
    int pt = p0 + sp;
    hbase = (lidx[pt] ? xl : xg) + (long)b * (512L * NN) + (pt & 2047);
  }
  int wo = tid >> 2, wc = (tid & 3) * 4;
  float acc[8][4];
#pragma unroll
  for (int i = 0; i < 8; ++i)
#pragma unroll
    for (int j = 0; j < 4; ++j) acc[i][j] = 0.f;

  for (int c0 = 0; c0 < 512; c0 += 16) {
    float4 wv = *(const float4*)(W + (long)(o0 + wo) * 512 + c0 + wc);
    Ws[wc + 0][wo] = wv.x; Ws[wc + 1][wo] = wv.y;
    Ws[wc + 2][wo] = wv.z; Ws[wc + 3][wo] = wv.w;
    long crow = (long)(c0 + scq) * NN;
#pragma unroll
    for (int e = 0; e < 8; ++e) Hs[scq + e][sp] = hbase[crow + (long)e * NN];
    __syncthreads();
#pragma unroll
    for (int cc = 0; cc < 16; ++cc) {
      float4 a0 = *(const float4*)&Ws[cc][ty * 8];
      float4 a1 = *(const float4*)&Ws[cc][ty * 8 + 4];
      float4 h = *(const float4*)&Hs[cc][tx * 4];
      acc[0][0] += a0.x * h.x; acc[0][1] += a0.x * h.y; acc[0][2] += a0.x * h.z; acc[0][3] += a0.x * h.w;
      acc[1][0] += a0.y * h.x; acc[1][1] += a0.y * h.y; acc[1][2] += a0.y * h.z; acc[1][3] += a0.y * h.w;
      acc[2][0] += a0.z * h.x; acc[2][1] += a0.z * h.y; acc[2][2] += a0.z * h.z; acc[2][3] += a0.z * h.w;
      acc[3][0] += a0.w * h.x; acc[3][1] += a0.w * h.y; acc[3][2] += a0.w * h.z; acc[3][3] += a0.w * h.w;
      acc[4][0] += a1.x * h.x; acc[4][1] += a1.x * h.y; acc[4][2] += a1.x * h.z; acc[4][3] += a1.x * h.w;
      acc[5][0] += a1.y * h.x; acc[5][1] += a1.y * h.y; acc[5][2] += a1.y * h.z; acc[5][3] += a1.y * h.w;
      acc[6][0] += a1.z * h.x; acc[6][1] += a1.z * h.y; acc[6][2] += a1.z * h.z; acc[6][3] += a1.z * h.w;
      acc[7][0] += a1.w * h.x; acc[7][1] += a1.w * h.y; acc[7][2] += a1.w * h.z; acc[7][3] += a1.w * h.w;
    }
    __syncthreads();
  }
#pragma unroll
  for (int i = 0; i < 8; ++i) {
    int o = o0 + ty * 8 + i;
    float4 v; v.x = acc[i][0]; v.y = acc[i][1]; v.z = acc[i][2]; v.w = acc[i][3];
    *(float4*)&h2[((long)b * 1024 + o) * NN + n0 + tx * 4] = v;
    float ss = acc[i][0] + acc[i][1] + acc[i][2] + acc[i][3];
    float sq = acc[i][0] * acc[i][0] + acc[i][1] * acc[i][1] +
               acc[i][2] * acc[i][2] + acc[i][3] * acc[i][3];
    for (int d = 16; d > 0; d >>= 1) {
      ss += __shfl_down(ss, d, 32);
      sq += __shfl_down(sq, d, 32);
    }
    if (tx == 0) {
      atomicAdd(&stats[o], ss);
      atomicAdd(&stats[1024 + o], sq);
    }
  }
}

// ---------------- BN+leaky (on the fly) + max/mean pool over N ------------
__global__ void k_gpool(const float* __restrict__ h2, const float* __restrict__ stats,
                        float* __restrict__ g) {
  int b = blockIdx.x / 1024, o = blockIdx.x % 1024;
  int tid = threadIdx.x;
  float mu = stats[o] * (1.f / 8192.f);
  float var = stats[1024 + o] * (1.f / 8192.f) - mu * mu;
  float rs = rsqrtf(var + EPSBN);
  const float* hr = h2 + ((long)b * 1024 + o) * NN;
  float mx = -FLT_MAX, sm = 0.f;
  for (int n = tid; n < NN; n += 256) {
    float v = (hr[n] - mu) * rs; v = v >= 0.f ? v : SLOPE * v;
    mx = fmaxf(mx, v); sm += v;
  }
  __shared__ float smx[256], ssm[256];
  smx[tid] = mx; ssm[tid] = sm; __syncthreads();
  for (int s = 128; s > 0; s >>= 1) {
    if (tid < s) { smx[tid] = fmaxf(smx[tid], smx[tid + s]); ssm[tid] += ssm[tid + s]; }
    __syncthreads();
  }
  if (tid == 0) { g[b * 2048 + o] = smx[0]; g[b * 2048 + 1024 + o] = ssm[0] * (1.f / NN); }
}

// ---------------- head: linear (+bias) (+BN over batch of 4, leaky) -------
__global__ void k_head(const float* __restrict__ gin, int CIN, const float* __restrict__ wl,
                       const float* __restrict__ bias, float* __restrict__ gout, int do_bn) {
  int f = blockIdx.x, tid = threadIdx.x, F = gridDim.x;
  const float* wr = wl + (long)f * CIN;
  float a0 = 0, a1 = 0, a2 = 0, a3 = 0;
  for (int c = tid; c < CIN; c += 256) {
    float wv = wr[c];
    a0 += wv * gin[c];         a1 += wv * gin[CIN + c];
    a2 += wv * gin[2 * CIN + c]; a3 += wv * gin[3 * CIN + c];
  }
  __shared__ float s0[256], s1[256], s2[256], s3[256];
  s0[tid] = a0; s1[tid] = a1; s2[tid] = a2; s3[tid] = a3; __syncthreads();
  for (int s = 128; s > 0; s >>= 1) {
    if (tid < s) { s0[tid] += s0[tid + s]; s1[tid] += s1[tid + s];
                   s2[tid] += s2[tid + s]; s3[tid] += s3[tid + s]; }
    __syncthreads();
  }
  if (tid == 0) {
    float z0 = s0[0], z1 = s1[0], z2 = s2[0], z3 = s3[0];
    if (bias) { float bb = bias[f]; z0 += bb; z1 += bb; z2 += bb; z3 += bb; }
    if (do_bn) {
      float mu = 0.25f * (z0 + z1 + z2 + z3);
      float var = 0.25f * (z0 * z0 + z1 * z1 + z2 * z2 + z3 * z3) - mu * mu;
      float rs = rsqrtf(var + EPSBN);
      z0 = (z0 - mu) * rs; z1 = (z1 - mu) * rs; z2 = (z2 - mu) * rs; z3 = (z3 - mu) * rs;
      z0 = z0 >= 0.f ? z0 : SLOPE * z0; z1 = z1 >= 0.f ? z1 : SLOPE * z1;
      z2 = z2 >= 0.f ? z2 : SLOPE * z2; z3 = z3 >= 0.f ? z3 : SLOPE * z3;
    }
    gout[0 * F + f] = z0; gout[1 * F + f] = z1; gout[2 * F + f] = z2; gout[3 * F + f] = z3;
  }
}

extern "C" void kernel_launch(void* const* d_in, const int* in_sizes, int n_in,
                              void* d_out, int out_size, void* d_ws, size_t ws_size,
                              hipStream_t stream) {
  const float* x   = (const float*)d_in[0];
  const int*   lidx= (const int*)d_in[1];
  const float* w1  = (const float*)d_in[3];
  const float* w2  = (const float*)d_in[4];
  const float* w3  = (const float*)d_in[5];
  const float* w4  = (const float*)d_in[6];
  const float* w5  = (const float*)d_in[7];
  const float* w6  = (const float*)d_in[8];
  const float* w7  = (const float*)d_in[9];
  const float* w8  = (const float*)d_in[10];
  const float* w9  = (const float*)d_in[11];
  const float* l1w = (const float*)d_in[12];
  const float* l2w = (const float*)d_in[13];
  const float* l2b = (const float*)d_in[14];
  const float* l3w = (const float*)d_in[15];
  const float* l3b = (const float*)d_in[16];
  float* out = (float*)d_out;

  float* ws    = (float*)d_ws;
  float* xxall = ws;                          // 7 * 8192 = 57344 (zeroed)
  float* stats = ws + 57344;                  // 4096 (zeroed)
  int*   idxb  = (int*)(ws + 61440);          // 163840 ints
  float* xloc  = ws + 225280;                 // 4,194,304
  float* xglb  = ws + 4419584;                // 4,194,304
  float* big   = ws + 8613888;                // 8,388,608 multi-use
  float* g     = ws + 17002496;               // 8192
  float* g1    = ws + 17010688;               // 2048
  float* g2    = ws + 17012736;               // 1024
  float* waall = ws + 17013760;               // 90496
  float* wdall = ws + 17104256;               // 90496

  float* srcb  = big;
  float* Zs    = big + 1048576;
  float* Zd    = big + 3145728;
  float* ymaxb = big + 5242880;
  int*   idxG2 = (int*)(big + 7340032);       // 163840 ints (dead until h2)
  float* h2    = big;
  int*   idxG  = (int*)xglb;                  // parked until G1 bnmax

  // xx slices
  float* xxS0 = xxall;
  float* xxS1 = xxall + 8192;
  float* xxS2 = xxall + 16384;
  float* xxS3 = xxall + 24576;
  float* xxS4 = xxall + 32768;
  float* xxS5 = xxall + 40960;
  float* xxS6 = xxall + 49152;

  // per-layer stats slices
  float* SL1 = stats + 0;    float* SL2 = stats + 128;
  float* SL3 = stats + 256;  float* SL4 = stats + 512;
  float* SG1 = stats + 1024; float* SG2 = stats + 1152;
  float* SG3 = stats + 1280; float* SG4 = stats + 1536;
  float* S9  = stats + 2048;

  const float invE = 1.f / (BB * NN * KNN);
  const long XS0 = 3L * NN;
  const long XS  = 512L * NN;
  const dim3 gknn(NN / 4, BB);       // layer-1 dual
  const dim3 gknn2(NN / 4, BB, 2);   // paired branches

  // ===== setup =====
  hipMemsetAsync(ws, 0, 61440 * sizeof(float), stream);
  k_wprep_all<<<dim3(128, 8), 256, 0, stream>>>(w1, w2, w3, w4, w5, w6, w7, w8,
                                                waall, wdall);
  k_xx3<<<128, 64, 0, stream>>>(x, xxS0);

  // ===== layer-1 kNN (both masks) =====
  k_knn_dual<3><<<gknn, 256, 0, stream>>>(x, XS0, xxS0, lidx, idxb, idxG);

  // ===== layer 1: L1 then G1 =====
  k_smooth<<<(BB * 3 * NN + 255) / 256, 256, 0, stream>>>(x, XS0, 3, idxb, srcb);
  k_zt2<3><<<dim3(32, 2, 4), 256, 0, stream>>>(srcb, 3L * NN, x, XS0,
                                               waall + 0, wdall + 0, 64, Zs, Zd);
  k_gmax<64, 8><<<BB * NN / 8, 64, 0, stream>>>(Zs, Zd, idxb, ymaxb, SL1);
  k_bnmax<<<(BB * 64 * NN + 255) / 256, 256, 0, stream>>>(ymaxb, SL1, 64, invE,
                                                          xloc + 0 * NN, XS, xxS1);
  k_zt2<3><<<dim3(32, 2, 4), 256, 0, stream>>>(x, XS0, x, XS0,
                                               waall + 45248, wdall + 45248, 64, Zs, Zd);
  k_gmax<64, 8><<<BB * NN / 8, 64, 0, stream>>>(Zs, Zd, idxG, ymaxb, SG1);
  k_bnmax<<<(BB * 64 * NN + 255) / 256, 256, 0, stream>>>(ymaxb, SG1, 64, invE,
                                                          xglb + 0 * NN, XS, xxS4);

  // ===== layer-2 kNN paired =====
  k_knn2<64><<<gknn2, 256, 0, stream>>>(xloc, xxS1, idxb,
                                        xglb, xxS4, idxG2, XS, lidx);
  // L2
  k_smooth<<<(BB * 64 * NN + 255) / 256, 256, 0, stream>>>(xloc, XS, 64, idxb, srcb);
  k_zt2<64><<<dim3(32, 2, 4), 256, 0, stream>>>(srcb, 64L * NN, xloc, XS,
                                                waall + 192, wdall + 192, 64, Zs, Zd);
  k_gmax<64, 8><<<BB * NN / 8, 64, 0, stream>>>(Zs, Zd, idxb, ymaxb, SL2);
  k_bnmax<<<(BB * 64 * NN + 255) / 256, 256, 0, stream>>>(ymaxb, SL2, 64, invE,
                                                          xloc + 64 * NN, XS, xxS2);
  // G2
  k_zt2<64><<<dim3(32, 2, 4), 256, 0, stream>>>(xglb, XS, xglb, XS,
                                                waall + 45440, wdall + 45440, 64, Zs, Zd);
  k_gmax<64, 8><<<BB * NN / 8, 64, 0, stream>>>(Zs, Zd, idxG2, ymaxb, SG2);
  k_bnmax<<<(BB * 64 * NN + 255) / 256, 256, 0, stream>>>(ymaxb, SG2, 64, invE,
                                                          xglb + 64 * NN, XS, xxS5);

  // ===== layer-3 kNN paired =====
  k_knn2<64><<<gknn2, 256, 0, stream>>>(xloc + 64 * NN, xxS2, idxb,
                                        xglb + 64 * NN, xxS5, idxG2, XS, lidx);
  // L3
  k_smooth<<<(BB * 64 * NN + 255) / 256, 256, 0, stream>>>(xloc + 64 * NN, XS, 64, idxb, srcb);
  k_zt2<64><<<dim3(32, 4, 4), 256, 0, stream>>>(srcb, 64L * NN, xloc + 64 * NN, XS,
                                                waall + 4288, wdall + 4288, 128, Zs, Zd);
  k_gmax<128, 16><<<BB * NN / 16, 128, 0, stream>>>(Zs, Zd, idxb, ymaxb, SL3);
  k_bnmax<<<(BB * 128 * NN + 255) / 256, 256, 0, stream>>>(ymaxb, SL3, 128, invE,
                                                           xloc + 128 * NN, XS, xxS3);
  // G3
  k_zt2<64><<<dim3(32, 4, 4), 256, 0, stream>>>(xglb + 64 * NN, XS, xglb + 64 * NN, XS,
                                                waall + 49536, wdall + 49536, 128, Zs, Zd);
  k_gmax<128, 16><<<BB * NN / 16, 128, 0, stream>>>(Zs, Zd, idxG2, ymaxb, SG3);
  k_bnmax<<<(BB * 128 * NN + 255) / 256, 256, 0, stream>>>(ymaxb, SG3, 128, invE,
                                                           xglb + 128 * NN, XS, xxS6);

  // ===== layer-4 kNN paired =====
  k_knn2<128><<<gknn2, 256, 0, stream>>>(xloc + 128 * NN, xxS3, idxb,
                                         xglb + 128 * NN, xxS6, idxG2, XS, lidx);
  // L4
  k_smooth<<<(BB * 128 * NN + 255) / 256, 256, 0, stream>>>(xloc + 128 * NN, XS, 128, idxb, srcb);
  k_zt2<128><<<dim3(32, 8, 4), 256, 0, stream>>>(srcb, 128L * NN, xloc + 128 * NN, XS,
                                                 waall + 12480, wdall + 12480, 256, Zs, Zd);
  k_gmax<256, 16><<<BB * NN / 16, 256, 0, stream>>>(Zs, Zd, idxb, ymaxb, SL4);
  k_bnmax<<<(BB * 256 * NN + 255) / 256, 256, 0, stream>>>(ymaxb, SL4, 256, invE,
                                                           xloc + 256 * NN, XS, nullptr);
  // G4
  k_zt2<128><<<dim3(32, 8, 4), 256, 0, stream>>>(xglb + 128 * NN, XS, xglb + 128 * NN, XS,
                                                 waall + 57728, wdall + 57728, 256, Zs, Zd);
  k_gmax<256, 16><<<BB * NN / 16, 256, 0, stream>>>(Zs, Zd, idxG2, ymaxb, SG4);
  k_bnmax<<<(BB * 256 * NN + 255) / 256, 256, 0, stream>>>(ymaxb, SG4, 256, invE,
                                                           xglb + 256 * NN, XS, nullptr);

  // ===== merge + w9 conv (SGEMM) + pool + head =====
  {
    dim3 g9(NN * BB / 128, 1024 / 64);
    k_gemm9<<<g9, 256, 0, stream>>>(w9, xloc, xglb, lidx, h2, S9);
  }
  k_gpool<<<BB * 1024, 256, 0, stream>>>(h2, S9, g);
  k_head<<<512, 256, 0, stream>>>(g, 2048, l1w, nullptr, g1, 1);
  k_head<<<256, 256, 0, stream>>>(g1, 512, l2w, l2b, g2, 1);
  k_head<<<40, 256, 0, stream>>>(g2, 256, l3w, l3b, out, 0);
}